// Round 3
// baseline (567.100 us; speedup 1.0000x reference)
//
#include <hip/hip_runtime.h>
#include <stdint.h>

#define B_ 64
#define S_ 512
#define K_ 1024
#define H_ 4096
#define C_ 32

typedef float  f32x4  __attribute__((ext_vector_type(4)));
typedef short  bf16x8 __attribute__((ext_vector_type(8)));
typedef unsigned short u16x8 __attribute__((ext_vector_type(8)));
typedef __attribute__((address_space(3))) unsigned int as3u32;
typedef const __attribute__((address_space(1))) unsigned int as1u32;

__device__ __forceinline__ unsigned short f2bf(float f) {
    unsigned u = __builtin_bit_cast(unsigned, f);
    u += 0x7fffu + ((u >> 16) & 1u);   // RNE
    return (unsigned short)(u >> 16);
}

// ---------------------------------------------------------------------------
// cat_ids may arrive as int32 or int64; detect on-device, normalize to i32.
__global__ void fix_cat_kernel(const void* __restrict__ cat_raw, int* __restrict__ cat32) {
    int t = threadIdx.x;                       // 64 threads = 1 wave
    const long long* c64 = (const long long*)cat_raw;
    const int*       c32 = (const int*)cat_raw;
    long long v = (t < 32) ? c64[t] : 0;
    int bad = (t < 32) && (v < 0 || v >= C_);
    unsigned long long m = __ballot(bad);
    if (m == 0ULL) {
        cat32[t] = (int)c64[t];
    } else {
        cat32[t] = c32[t];
    }
}

// ---------------------------------------------------------------------------
// x f32 -> bf16, vectorized 8 elems/thread
__global__ __launch_bounds__(256) void cvt_x_kernel(const float4* __restrict__ x,
                                                    uint4* __restrict__ xb, int n8) {
    int stride = gridDim.x * blockDim.x;
    for (int i = blockIdx.x * blockDim.x + threadIdx.x; i < n8; i += stride) {
        float4 a = x[2 * i], b = x[2 * i + 1];
        uint4 o;
        o.x = (unsigned)f2bf(a.x) | ((unsigned)f2bf(a.y) << 16);
        o.y = (unsigned)f2bf(a.z) | ((unsigned)f2bf(a.w) << 16);
        o.z = (unsigned)f2bf(b.x) | ((unsigned)f2bf(b.y) << 16);
        o.w = (unsigned)f2bf(b.z) | ((unsigned)f2bf(b.w) << 16);
        xb[i] = o;
    }
}

// ---------------------------------------------------------------------------
// W [C][K][H] f32 -> WT [C][H][K] bf16, LDS-tiled 64x64 transpose
__global__ __launch_bounds__(256) void cvt_w_kernel(const float* __restrict__ W,
                                                    unsigned short* __restrict__ WT) {
    __shared__ unsigned short tile[64 * 68];   // [k][n], padded stride 68
    const int nt = blockIdx.x;                 // 64 n-tiles
    const int kt = blockIdx.y;                 // 16 k-tiles
    const int c  = blockIdx.z;                 // 32 categories
    const int t  = threadIdx.x;

    const float* Wp = W + ((size_t)c << 22);
#pragma unroll
    for (int p = 0; p < 4; ++p) {
        int task = p * 256 + t;
        int kr = task >> 4;
        int nc = (task & 15) << 2;
        float4 v = *(const float4*)(Wp + (size_t)(kt * 64 + kr) * H_ + nt * 64 + nc);
        tile[kr * 68 + nc + 0] = f2bf(v.x);
        tile[kr * 68 + nc + 1] = f2bf(v.y);
        tile[kr * 68 + nc + 2] = f2bf(v.z);
        tile[kr * 68 + nc + 3] = f2bf(v.w);
    }
    __syncthreads();

    unsigned short* WTp = WT + ((size_t)c << 22);
#pragma unroll
    for (int q = 0; q < 2; ++q) {
        int task = q * 256 + t;
        int nl = task >> 3;
        int ko = (task & 7) << 3;
        u16x8 o;
#pragma unroll
        for (int j = 0; j < 8; ++j) o[j] = tile[(ko + j) * 68 + nl];
        *(u16x8*)(WTp + (size_t)(nt * 64 + nl) * K_ + kt * 64 + ko) = o;
    }
}

// ---------------------------------------------------------------------------
// Batched GEMM, 256x256 tile, BK=32, 8 waves (2Mx4N), per-wave 128x64.
// 4-deep LDS ring (128 KiB), prefetch 3 K-tiles ahead, slot XOR-swizzle (T2).
// NEW this round: m201-style phase template (T3+T4+T5):
//   2 phases per K-tile, each {ds_read subtile (8 or 4 x b128) || 2 x
//   global_load_lds -> s_barrier -> lgkmcnt(0)+sched_barrier -> setprio(1)
//   -> 16 MFMA -> setprio(0) -> s_barrier}; the one counted vmcnt(8) per
//   tile is folded into the tile's last barrier (never 0 in the main loop).
__global__ __launch_bounds__(512, 2) void gemm2_kernel(
    const unsigned short* __restrict__ xb,   // [B][S][K] bf16
    const unsigned short* __restrict__ WT,   // [C][H][K] bf16
    const float* __restrict__ bias,          // [C][H]
    const int* __restrict__ cat,             // [B]
    float* __restrict__ out)                 // [B][S][H]
{
    extern __shared__ __align__(16) char smem[];   // 4 bufs x (A 16K | B 16K)

    const int t    = threadIdx.x;
    const int lane = t & 63;
    const int w    = t >> 6;            // 0..7
    const int wm   = w >> 2;            // 0..1
    const int wn   = w & 3;             // 0..3
    const int lo   = lane & 15;
    const int hi   = lane >> 4;         // 0..3

    // XCD-aware bijective swizzle (2048 % 8 == 0)
    const int wg = (blockIdx.x & 7) * 256 + (blockIdx.x >> 3);
    const int bn = wg & 15;
    const int bm = (wg >> 4) & 1;
    const int bb = wg >> 5;

    const int c = cat[bb];

    const unsigned short* Ap = xb + (size_t)bb * (S_ * K_) + (size_t)(bm * 256) * K_;
    const unsigned short* Bp = WT + (size_t)c * ((size_t)H_ * K_) + (size_t)(bn * 256) * K_;

    // staging: chunk ch = i*8+w covers rows [ch*16, ch*16+16), 64B per row.
    // linear LDS dest; global source pre-swizzled (m173): logical k-slot =
    // (lane&3) ^ ((row>>2)&3) = (lane&3) ^ hi.
    const int srow  = lane >> 2;
    const int sslot = (lane & 3) ^ hi;
    const char* srcA[2]; const char* srcB[2];
    int offA[2], offB[2];
#pragma unroll
    for (int i = 0; i < 2; ++i) {
        int ch = i * 8 + w;
        int r  = ch * 16 + srow;
        srcA[i] = (const char*)(Ap + (size_t)r * K_ + sslot * 8);
        srcB[i] = (const char*)(Bp + (size_t)r * K_ + sslot * 8);
        offA[i] = ch * 1024;
        offB[i] = 16384 + ch * 1024;
    }

    // fragment read offsets: row stride 64B, swizzled slot = hi ^ ((row>>2)&3)
    const int xslot = (hi ^ ((lo >> 2) & 3)) << 4;
    int aoff[8], boff[4];
#pragma unroll
    for (int mi = 0; mi < 8; ++mi) aoff[mi] = (wm * 128 + mi * 16 + lo) * 64 + xslot;
#pragma unroll
    for (int ni = 0; ni < 4; ++ni) boff[ni] = 16384 + (wn * 64 + ni * 16 + lo) * 64 + xslot;

    f32x4 acc[8][4];
#pragma unroll
    for (int mi = 0; mi < 8; ++mi)
#pragma unroll
        for (int ni = 0; ni < 4; ++ni) acc[mi][ni] = f32x4{0.f, 0.f, 0.f, 0.f};

#define STAGE_A(s_, d_) do {                                                      \
    const int sa__ = (s_);                                                        \
    char* da__ = smem + (d_) * 32768;                                             \
    __builtin_amdgcn_global_load_lds((as1u32*)(srcA[0] + sa__ * 64),              \
                                     (as3u32*)(da__ + offA[0]), 16, 0, 0);        \
    __builtin_amdgcn_global_load_lds((as1u32*)(srcA[1] + sa__ * 64),              \
                                     (as3u32*)(da__ + offA[1]), 16, 0, 0);        \
} while (0)
#define STAGE_B(s_, d_) do {                                                      \
    const int sb__ = (s_);                                                        \
    char* db__ = smem + (d_) * 32768;                                             \
    __builtin_amdgcn_global_load_lds((as1u32*)(srcB[0] + sb__ * 64),              \
                                     (as3u32*)(db__ + offB[0]), 16, 0, 0);        \
    __builtin_amdgcn_global_load_lds((as1u32*)(srcB[1] + sb__ * 64),              \
                                     (as3u32*)(db__ + offB[1]), 16, 0, 0);        \
} while (0)

    // prologue: stage K-tiles 0,1,2 into ring slots 0,1,2 (12 vmem instrs);
    // guarantee tile 0 landed (vmcnt(8)) before any phase-0 ds_read.
    STAGE_A(0, 0); STAGE_B(0, 0);
    STAGE_A(1, 1); STAGE_B(1, 1);
    STAGE_A(2, 2); STAGE_B(2, 2);
    asm volatile("s_waitcnt vmcnt(8)" ::: "memory");
    __builtin_amdgcn_s_barrier();

    // main loop: 32 K-tiles, 2 phases each. Issue order per tile: A-half
    // (phase 0) then B-half (phase 1) of tile tt+3. At the tile-end vmcnt(8),
    // outstanding <= 12 (tiles tt+1..tt+3); the oldest 4 (= tile tt+1, needed
    // next) are drained, 8 stay in flight. Tail wraps (re-stages tiles 0..2
    // into dead slots) so counts stay uniform.
#pragma unroll 4
    for (int tt = 0; tt < 32; ++tt) {
        const char* buf = smem + (tt & 3) * 32768;
        const int sN = (tt + 3) & 31, dN = (tt + 3) & 3;
        bf16x8 av[4], bv[4], aw[4];

        // ---- phase 0: read av[0..3], bv[0..3]; stage A-half of tile tt+3
#pragma unroll
        for (int mi = 0; mi < 4; ++mi) av[mi] = *(const bf16x8*)(buf + aoff[mi]);
#pragma unroll
        for (int ni = 0; ni < 4; ++ni) bv[ni] = *(const bf16x8*)(buf + boff[ni]);
        STAGE_A(sN, dN);
        asm volatile("" ::: "memory");          // pin reads/stage before barrier
        __builtin_amdgcn_s_barrier();
        asm volatile("s_waitcnt lgkmcnt(0)" ::: "memory");
        __builtin_amdgcn_sched_barrier(0);
        __builtin_amdgcn_s_setprio(1);
#pragma unroll
        for (int mi = 0; mi < 4; ++mi)
#pragma unroll
            for (int ni = 0; ni < 4; ++ni)
                acc[mi][ni] = __builtin_amdgcn_mfma_f32_16x16x32_bf16(
                    bv[ni], av[mi], acc[mi][ni], 0, 0, 0);
        __builtin_amdgcn_s_setprio(0);
        __builtin_amdgcn_s_barrier();

        // ---- phase 1: read aw[0..3] (mi 4..7); stage B-half of tile tt+3
#pragma unroll
        for (int mi = 0; mi < 4; ++mi) aw[mi] = *(const bf16x8*)(buf + aoff[mi + 4]);
        STAGE_B(sN, dN);
        asm volatile("" ::: "memory");
        __builtin_amdgcn_s_barrier();
        asm volatile("s_waitcnt lgkmcnt(0)" ::: "memory");
        __builtin_amdgcn_sched_barrier(0);
        __builtin_amdgcn_s_setprio(1);
#pragma unroll
        for (int mi = 0; mi < 4; ++mi)
#pragma unroll
            for (int ni = 0; ni < 4; ++ni)
                acc[mi + 4][ni] = __builtin_amdgcn_mfma_f32_16x16x32_bf16(
                    bv[ni], aw[mi], acc[mi + 4][ni], 0, 0, 0);
        __builtin_amdgcn_s_setprio(0);
        asm volatile("s_waitcnt vmcnt(8)" ::: "memory");   // counted, never 0
        __builtin_amdgcn_s_barrier();
    }
#undef STAGE_A
#undef STAGE_B

    // drain wrap-staged loads before block exit
    asm volatile("s_waitcnt vmcnt(0)" ::: "memory");

    // epilogue. Operand-swapped D layout: n = frag_base + hi*4 + reg, m = lo.
    float* outp = out + ((size_t)bb * S_ + bm * 256 + wm * 128) * H_ + bn * 256 + wn * 64;
    const float* bp = bias + (size_t)c * H_ + bn * 256 + wn * 64;
#pragma unroll
    for (int ni = 0; ni < 4; ++ni) {
        const int nf = ni * 16 + hi * 4;
        const f32x4 b4 = *(const f32x4*)(bp + nf);
#pragma unroll
        for (int mi = 0; mi < 8; ++mi) {
            const int mf = mi * 16 + lo;
            f32x4 v = acc[mi][ni];
            v.x += b4.x; v.y += b4.y; v.z += b4.z; v.w += b4.w;
            *(f32x4*)(outp + (size_t)mf * H_ + nf) = v;
        }
    }
}

// ---------------------------------------------------------------------------
// Fallback (ws too small): correct but slow f32 vector-ALU kernel.
__global__ __launch_bounds__(256) void fallback_kernel(
    const float* __restrict__ x, const int* __restrict__ cat,
    const float* __restrict__ W, const float* __restrict__ bias,
    float* __restrict__ out)
{
    __shared__ float xs[K_];
    int bs = blockIdx.x;
    int bb = bs >> 9;
    int c  = cat[bb];
    const float* xp = x + (size_t)bs * K_;
    for (int i = threadIdx.x; i < K_ / 4; i += 256)
        ((float4*)xs)[i] = ((const float4*)xp)[i];
    __syncthreads();

    int h = blockIdx.y * 1024 + threadIdx.x * 4;
    const float* Wp = W + (size_t)c * K_ * H_ + h;
    float a0 = 0.f, a1 = 0.f, a2 = 0.f, a3 = 0.f;
    for (int k = 0; k < K_; ++k) {
        float xv = xs[k];
        float4 wv = *(const float4*)(Wp + (size_t)k * H_);
        a0 += xv * wv.x; a1 += xv * wv.y; a2 += xv * wv.z; a3 += xv * wv.w;
    }
    float4 bv = *(const float4*)(bias + c * H_ + h);
    float4 o; o.x = a0 + bv.x; o.y = a1 + bv.y; o.z = a2 + bv.z; o.w = a3 + bv.w;
    *(float4*)(out + (size_t)bs * H_ + h) = o;
}

// ---------------------------------------------------------------------------
extern "C" void kernel_launch(void* const* d_in, const int* in_sizes, int n_in,
                              void* d_out, int out_size, void* d_ws, size_t ws_size,
                              hipStream_t stream) {
    const float* x        = (const float*)d_in[0];
    const void*  cat_raw  = d_in[1];
    const float* W        = (const float*)d_in[2];
    const float* bias     = (const float*)d_in[3];
    float*       out      = (float*)d_out;

    const size_t CAT_BYTES = 256;
    const size_t XB_OFF    = 256;
    const size_t XB_BYTES  = (size_t)B_ * S_ * K_ * 2;          // 64 MiB
    const size_t WT_OFF    = XB_OFF + XB_BYTES;
    const size_t WT_BYTES  = (size_t)C_ * H_ * K_ * 2;          // 256 MiB
    const size_t NEED      = WT_OFF + WT_BYTES;

    const int* catp;
    if (ws_size >= CAT_BYTES) {
        int* cat32 = (int*)d_ws;
        fix_cat_kernel<<<1, 64, 0, stream>>>(cat_raw, cat32);
        catp = cat32;
    } else {
        catp = (const int*)cat_raw;
    }

    if (ws_size >= NEED) {
        unsigned short* xb = (unsigned short*)((char*)d_ws + XB_OFF);
        unsigned short* WT = (unsigned short*)((char*)d_ws + WT_OFF);
        cvt_x_kernel<<<2048, 256, 0, stream>>>((const float4*)x, (uint4*)xb,
                                               (int)((size_t)B_ * S_ * K_ / 8));
        dim3 gw(64, 16, 32);
        cvt_w_kernel<<<gw, 256, 0, stream>>>(W, WT);
        hipFuncSetAttribute((const void*)gemm2_kernel,
                            hipFuncAttributeMaxDynamicSharedMemorySize, 131072);
        gemm2_kernel<<<2048, 512, 131072, stream>>>(xb, WT, bias, catp, out);
    } else {
        dim3 g(B_ * S_, H_ / 1024);
        fallback_kernel<<<g, 256, 0, stream>>>(x, catp, W, bias, out);
    }
}